// Round 9
// baseline (179.097 us; speedup 1.0000x reference)
//
#include <hip/hip_runtime.h>
#include <math.h>

#define DIM 256
#define HD 32
#define KSCALE (0.17677669529663687f * 1.44269504088896340736f)  /* SCALE*log2(e) */
#define EPS 1e-5f

typedef __attribute__((ext_vector_type(8))) short short8;   // 8 bf16 = 4 VGPRs
typedef __attribute__((ext_vector_type(4))) float f32x4;

union U8 { uint4 u; short8 s; };

__device__ inline unsigned short f2bf(float f) {
    union { float f; unsigned u; } v; v.f = f;
    unsigned r = v.u + 0x7FFF + ((v.u >> 16) & 1);   // RNE
    return (unsigned short)(r >> 16);
}
__device__ inline float bf2f(unsigned short h) {
    union { unsigned u; float f; } v; v.u = ((unsigned)h) << 16;
    return v.f;
}
// pack two fp32 -> two bf16 (round-half-up) in one dword: 3 VALU ops
__device__ inline unsigned pk2bf(float a, float b) {
    unsigned ua = __float_as_uint(a) + 0x8000u;
    unsigned ub = __float_as_uint(b) + 0x8000u;
    return __builtin_amdgcn_perm(ub, ua, 0x07060302u);  // {low=bf(a), high=bf(b)}
}
__device__ inline uint4 pk8bf(float4 a, float4 b) {
    return make_uint4(pk2bf(a.x, a.y), pk2bf(a.z, a.w),
                      pk2bf(b.x, b.y), pk2bf(b.z, b.w));
}
// unpack bf16x2 dword -> 2 fp32
__device__ inline void up2(unsigned u, float& a, float& b) {
    a = __uint_as_float(u << 16);
    b = __uint_as_float(u & 0xffff0000u);
}
// async global->LDS DMA, 16B/lane; lds dest = wave-uniform base + lane*16
__device__ inline void gl_lds16(const unsigned short* g, unsigned short* l) {
    __builtin_amdgcn_global_load_lds(
        (const __attribute__((address_space(1))) unsigned int*)g,
        (__attribute__((address_space(3))) unsigned int*)l, 16, 0, 0);
}
#define MFMA16(a, b, c) __builtin_amdgcn_mfma_f32_16x16x32_bf16(a, b, c, 0, 0, 0)
#define EXP2(x) __builtin_amdgcn_exp2f(x)

// ---------------------------------------------------------------------------
// Weights prep: transposed bf16 WqT/WkvT/projT [N][K], conv BwT[o][q*256+i],
// plus zero-fill of the attention pad tiles (4096 elems). Grid 2064 x 256.
// ---------------------------------------------------------------------------
__global__ __launch_bounds__(256) void prep_w(
    const float* __restrict__ Wq, const float* __restrict__ Wkv,
    const float* __restrict__ projw, const float* __restrict__ srw,
    unsigned short* __restrict__ WqT, unsigned short* __restrict__ WkvT,
    unsigned short* __restrict__ projT, unsigned short* __restrict__ BwT,
    unsigned short* __restrict__ pads)
{
    int idx = blockIdx.x * 256 + threadIdx.x;
    if (idx < 65536) { int n = idx >> 8, k = idx & 255; WqT[idx] = f2bf(Wq[(k << 8) + n]); return; }
    idx -= 65536;
    if (idx < 131072) { int n = idx >> 8, k = idx & 255; WkvT[idx] = f2bf(Wkv[(k << 9) + n]); return; }
    idx -= 131072;
    if (idx < 65536) { int n = idx >> 8, k = idx & 255; projT[idx] = f2bf(projw[(k << 8) + n]); return; }
    idx -= 65536;
    if (idx < 262144) { int o = idx >> 10, rem = idx & 1023, q = rem >> 8, i = rem & 255;
                        BwT[idx] = f2bf(srw[(o << 10) + (i << 2) + q]); return; }
    idx -= 262144;
    pads[idx] = 0;   // kpad+vpad (4096 elems)
}

// ---------------------------------------------------------------------------
// Implicit-im2col conv (K=1024), A staged from fp32 with on-the-fly bf16
// pack. Grid 164 flat blocks (n0 = (bid&3)*64, myi = bid>>2: 0..24 x, 25..40 y).
// ---------------------------------------------------------------------------
__global__ __launch_bounds__(256) void conv_kernel(
    const float* __restrict__ x, const float* __restrict__ y,
    const unsigned short* __restrict__ BwT, const float* __restrict__ srb,
    unsigned short* __restrict__ redx, unsigned short* __restrict__ redy)
{
    __shared__ __align__(16) unsigned short At[64][32];
    __shared__ __align__(16) unsigned short Btile[64][32];
    const int tid = threadIdx.x;
    const int lane = tid & 63, w = tid >> 6;
    const int c = lane & 15, quad = lane >> 4;
    const int srow = tid >> 2, sch = (tid & 3) << 3;
    const int bid = blockIdx.x;
    f32x4 acc[4] = {};
    const int rl = (w << 4) + (quad << 2);

    const int n0 = (bid & 3) << 6, myi = bid >> 2;
    const float* Xb; unsigned short* Cb; int W, W2, m0;
    if (myi < 25) { Xb = x; Cb = redx; W = 80; W2 = 40; m0 = myi * 64; }
    else {
        const int r = myi - 25, b = r >> 2;
        Xb = y + (size_t)b * 262144; Cb = redy + (size_t)b * 65536;
        W = 32; W2 = 16; m0 = (r & 3) * 64;
    }
    const int p = m0 + srow;
    const int oy = p / W2, ox = p - oy * W2;
    const unsigned short* Bp = BwT + (size_t)(n0 + srow) * 1024 + sch;

    auto addrA = [&](int k0) {
        const int qq = k0 >> 8;
        const int rrow = (2 * oy + (qq >> 1)) * W + 2 * ox + (qq & 1);
        return Xb + (size_t)rrow * DIM + (k0 & 255) + sch;
    };

    const float* ap = addrA(0);
    float4 a0 = *(const float4*)ap, a1 = *(const float4*)(ap + 4);
    uint4 bn = *(const uint4*)Bp;
    for (int k0 = 0; k0 < 1024; k0 += 32) {
        *(uint4*)&At[srow][sch]    = pk8bf(a0, a1);
        *(uint4*)&Btile[srow][sch] = bn;
        if (k0 < 992) {
            const float* np = addrA(k0 + 32);
            a0 = *(const float4*)np; a1 = *(const float4*)(np + 4);
            bn = *(const uint4*)(Bp + k0 + 32);
        }
        __syncthreads();
        short8 a = *(short8*)&At[(w << 4) + c][quad << 3];
        #pragma unroll
        for (int nb = 0; nb < 4; ++nb) {
            short8 b = *(short8*)&Btile[(nb << 4) + c][quad << 3];
            acc[nb] = MFMA16(a, b, acc[nb]);
        }
        __syncthreads();
    }
    #pragma unroll
    for (int nb = 0; nb < 4; ++nb) {
        const int col = n0 + (nb << 4) + c;
        const float bv = srb[col];
        #pragma unroll
        for (int r = 0; r < 4; ++r)
            Cb[(size_t)(m0 + rl + r) * DIM + col] = f2bf(acc[nb][r] + bv);
    }
}

// ---------------------------------------------------------------------------
// KV projection with fused LayerNorm on A-rows. Outputs in attention's
// swizzled per-(head, 64-key-tile) 4KB layouts:
//   K: ksw[h][tile][(d>>3)*64 + key]*8 + (d&7)          (pre-scaled by KSCALE)
//   V: vsw[h][tile][ half*1024 + (d>>4)*512 + ((kl>>2)&3)*128 + (d&15)*8
//                    + (kl>>4)*4 + (kl&3) ],  half=key>>5, kl=key&31
// ---------------------------------------------------------------------------
__global__ __launch_bounds__(256) void kvln_kernel(
    const unsigned short* __restrict__ redx, const unsigned short* __restrict__ redy,
    const unsigned short* __restrict__ WkvT,
    const float* __restrict__ g, const float* __restrict__ bta,
    unsigned short* __restrict__ kswx, unsigned short* __restrict__ vswx,
    unsigned short* __restrict__ kswy, unsigned short* __restrict__ vswy)
{
    __shared__ __align__(16) unsigned short At[64][32];
    __shared__ __align__(16) unsigned short Btile[64][32];
    const int tid = threadIdx.x;
    const int lane = tid & 63, w = tid >> 6;
    const int c = lane & 15, quad = lane >> 4;
    const int srow = tid >> 2, sch = (tid & 3) << 3;
    const int bid = blockIdx.x;
    const int n0 = (bid & 7) << 6, mg = (bid >> 3) << 6;
    const unsigned short* Ab = (mg < 1600) ? redx + (size_t)mg * 256
                                           : redy + (size_t)(mg - 1600) * 256;
    const unsigned short* Arow = Ab + (size_t)srow * 256 + sch;

    // ---- row stats ----
    uint4 araw[8];
    float s1 = 0.f, s2 = 0.f;
    #pragma unroll
    for (int ci = 0; ci < 8; ++ci) {
        araw[ci] = *(const uint4*)(Arow + (ci << 5));
        const unsigned* du = (const unsigned*)&araw[ci];
        #pragma unroll
        for (int dd = 0; dd < 4; ++dd) {
            float a, b; up2(du[dd], a, b);
            s1 += a + b; s2 += a * a + b * b;
        }
    }
    s1 += __shfl_xor(s1, 1); s1 += __shfl_xor(s1, 2);
    s2 += __shfl_xor(s2, 1); s2 += __shfl_xor(s2, 2);
    const float mean = s1 * (1.0f / 256.0f);
    const float var  = s2 * (1.0f / 256.0f) - mean * mean;
    const float rstd = rsqrtf(var + EPS);

    // ---- apply LN, repack to bf16 ----
    #pragma unroll
    for (int ci = 0; ci < 8; ++ci) {
        const int ch = (ci << 5) + sch;
        float4 g0 = *(const float4*)(g + ch),   g1 = *(const float4*)(g + ch + 4);
        float4 b0 = *(const float4*)(bta + ch), b1 = *(const float4*)(bta + ch + 4);
        const unsigned* du = (const unsigned*)&araw[ci];
        float v[8];
        #pragma unroll
        for (int dd = 0; dd < 4; ++dd) up2(du[dd], v[2 * dd], v[2 * dd + 1]);
        float4 o0 = make_float4(fmaf((v[0] - mean) * rstd, g0.x, b0.x),
                                fmaf((v[1] - mean) * rstd, g0.y, b0.y),
                                fmaf((v[2] - mean) * rstd, g0.z, b0.z),
                                fmaf((v[3] - mean) * rstd, g0.w, b0.w));
        float4 o1 = make_float4(fmaf((v[4] - mean) * rstd, g1.x, b1.x),
                                fmaf((v[5] - mean) * rstd, g1.y, b1.y),
                                fmaf((v[6] - mean) * rstd, g1.z, b1.z),
                                fmaf((v[7] - mean) * rstd, g1.w, b1.w));
        araw[ci] = pk8bf(o0, o1);
    }

    // ---- GEMM k-loop ----
    const unsigned short* Bp = WkvT + (size_t)(n0 + srow) * 256 + sch;
    uint4 bn = *(const uint4*)Bp;
    f32x4 acc[4] = {};
    for (int k0 = 0; k0 < 256; k0 += 32) {
        *(uint4*)&At[srow][sch]    = araw[k0 >> 5];
        *(uint4*)&Btile[srow][sch] = bn;
        if (k0 < 224) bn = *(const uint4*)(Bp + k0 + 32);
        __syncthreads();
        short8 a = *(short8*)&At[(w << 4) + c][quad << 3];
        #pragma unroll
        for (int nb = 0; nb < 4; ++nb) {
            short8 b = *(short8*)&Btile[(nb << 4) + c][quad << 3];
            acc[nb] = MFMA16(a, b, acc[nb]);
        }
        __syncthreads();
    }

    const int rl = (w << 4) + (quad << 2);        // first of 4 key rows (in-tile)
    const int r0 = mg - 1600;                     // y row offset (if y)
    const int half = rl >> 5, kl0 = rl & 31;
    const int vkeyoff = (half << 10) + (((kl0 >> 2) & 3) << 7) + ((kl0 >> 4) << 2);
    #pragma unroll
    for (int nb = 0; nb < 4; ++nb) {
        const int col = n0 + (nb << 4) + c;
        if (col < 256) {
            const int hh = col >> 5, d = col & 31;
            unsigned short* base = (mg < 1600)
                ? kswx + ((size_t)(hh * 25 + (mg >> 6)) << 11)
                : kswy + ((size_t)(r0 >> 8) << 16) + ((size_t)((hh << 2) + ((r0 >> 6) & 3)) << 11);
            unsigned short* dst = base + (((d >> 3) << 9)) + (d & 7);
            #pragma unroll
            for (int r = 0; r < 4; ++r)
                dst[(rl + r) << 3] = f2bf(acc[nb][r] * KSCALE);
        } else {
            const int hd = col - 256, hv = hd >> 5, d = hd & 31;
            unsigned short* base = (mg < 1600)
                ? vswx + ((size_t)(hv * 25 + (mg >> 6)) << 11)
                : vswy + ((size_t)(r0 >> 8) << 16) + ((size_t)((hv << 2) + ((r0 >> 6) & 3)) << 11);
            unsigned lo = (unsigned)f2bf(acc[nb][0]) | ((unsigned)f2bf(acc[nb][1]) << 16);
            unsigned hi = (unsigned)f2bf(acc[nb][2]) | ((unsigned)f2bf(acc[nb][3]) << 16);
            *(uint2*)(base + vkeyoff + ((d >> 4) << 9) + ((d & 15) << 3)) =
                make_uint2(lo, hi);
        }
    }
}

// ---------------------------------------------------------------------------
// Batch-mean of support KV in swizzled layout (elementwise; layout-agnostic).
// ---------------------------------------------------------------------------
__global__ __launch_bounds__(256) void kvmean_kernel(
    const unsigned short* __restrict__ kswy, const unsigned short* __restrict__ vswy,
    unsigned short* __restrict__ kmsw, unsigned short* __restrict__ vmsw)
{
    int idx = blockIdx.x * 256 + threadIdx.x;
    const unsigned short* s; unsigned short* dv; int e;
    if (idx < 65536) { s = kswy; dv = kmsw; e = idx; }
    else             { s = vswy; dv = vmsw; e = idx - 65536; }
    float sm = bf2f(s[e]) + bf2f(s[e + 65536]) + bf2f(s[e + 131072]) + bf2f(s[e + 196608]);
    dv[e] = f2bf(0.25f * sm);
}

// ---------------------------------------------------------------------------
// MFMA flash attention with FUSED q-projection. Per block: Q[64x32] computed
// by a 16-MFMA/wave mini-GEMM (A = WqT rows, B = fp32 x/y rows packed bf16),
// bounced once through LDS into B-frag layout; then r8's key-split flash loop
// (128-key double-tiles, one barrier each, in-register sigma-packed P).
// Output goes to ob (bf16). Grid 1312 flat blocks.
// ---------------------------------------------------------------------------
__global__ __launch_bounds__(256) void attn_mfma(
    const float* __restrict__ xf, const float* __restrict__ yf,
    const unsigned short* __restrict__ WqT,
    unsigned short* __restrict__ obx, unsigned short* __restrict__ oby,
    const unsigned short* __restrict__ kswx, const unsigned short* __restrict__ vswx,
    const unsigned short* __restrict__ kmsw, const unsigned short* __restrict__ vmsw,
    const unsigned short* __restrict__ kswy, const unsigned short* __restrict__ vswy,
    const unsigned short* __restrict__ kpad, const unsigned short* __restrict__ vpad)
{
    __shared__ __align__(16) unsigned short KV[2][8192];  // [buf][K0 K1 V0 V1]
    __shared__ __align__(16) unsigned short Qbuf[64][40]; // Q in B-frag layout
    __shared__ __align__(16) float lsumLDS[4][64];

    const int tid = threadIdx.x;
    const int lane = tid & 63, w = tid >> 6;
    const int c = lane & 15, quad = lane >> 4;

    const int bid = blockIdx.x;
    const float* qsrc; unsigned short* ob;
    const unsigned short *k1, *v1, *k2, *v2;
    int h, qoff;
    if (bid < 800) {
        h = bid / 100; qoff = (bid - h * 100) * 64;
        qsrc = xf; ob = obx;
        k1 = kswx + ((size_t)h * 25 << 11); v1 = vswx + ((size_t)h * 25 << 11);
        k2 = kmsw + ((size_t)h << 13);      v2 = vmsw + ((size_t)h << 13);
    } else {
        const int idx = bid - 800, b = idx >> 7, rem = idx & 127;
        h = rem >> 4; qoff = b * 1024 + (rem & 15) * 64;
        qsrc = yf; ob = oby;
        k1 = kswx + ((size_t)h * 25 << 11); v1 = vswx + ((size_t)h * 25 << 11);
        k2 = kswy + ((size_t)b << 16) + ((size_t)h << 13);
        v2 = vswy + ((size_t)b << 16) + ((size_t)h << 13);
    }

    auto ksrc = [&](int t) -> const unsigned short* {
        if (t < 25) return k1 + (t << 11);
        if (t < 29) return k2 + ((t - 25) << 11);
        return kpad;
    };
    auto vsrc = [&](int t) -> const unsigned short* {
        if (t < 25) return v1 + (t << 11);
        if (t < 29) return v2 + ((t - 25) << 11);
        return vpad;
    };
    const int sg = (w << 9) + (lane << 3);
    auto stage = [&](int i, int pb) {        // stage tiles 2i, 2i+1
        #pragma unroll
        for (int tt = 0; tt < 2; ++tt) {
            const int t = 2 * i + tt;
            gl_lds16(ksrc(t) + sg, &KV[pb][(tt << 11) + (w << 9)]);
            gl_lds16(vsrc(t) + sg, &KV[pb][4096 + (tt << 11) + (w << 9)]);
        }
    };

    const f32x4 zero = {0.f, 0.f, 0.f, 0.f};

    stage(0, 0);   // KV DMA in flight while Q is computed

    // ---- fused q-projection: C = Q^T[d 0..32][qrow 16w..16w+16] ----
    {
        const float* xr = qsrc + (size_t)(qoff + (w << 4) + c) * DIM;
        const unsigned short* wqA = WqT + (size_t)(h * HD + c) * DIM + (quad << 3);
        f32x4 qa0 = zero, qa1 = zero;
        #pragma unroll
        for (int kk = 0; kk < 8; ++kk) {
            const int ko = (kk << 5) + (quad << 3);
            float4 b0 = *(const float4*)(xr + ko);
            float4 b1 = *(const float4*)(xr + ko + 4);
            U8 bfr; bfr.u = pk8bf(b0, b1);
            short8 a0 = *(const short8*)(wqA + (kk << 5));
            short8 a1 = *(const short8*)(wqA + 16 * DIM + (kk << 5));
            qa0 = MFMA16(a0, bfr.s, qa0);
            qa1 = MFMA16(a1, bfr.s, qa1);
        }
        // lane holds Q^T[d=16md+4quad+r][qrow=16w+c] -> Qbuf[qrow][d], b64 each
        *(uint2*)&Qbuf[(w << 4) + c][(quad << 2)] =
            make_uint2(pk2bf(qa0[0], qa0[1]), pk2bf(qa0[2], qa0[3]));
        *(uint2*)&Qbuf[(w << 4) + c][16 + (quad << 2)] =
            make_uint2(pk2bf(qa1[0], qa1[1]), pk2bf(qa1[2], qa1[3]));
    }
    __syncthreads();   // Qbuf ready + stage(0) drained

    short8 qf[4];
    #pragma unroll
    for (int nb = 0; nb < 4; ++nb)
        qf[nb] = *(const short8*)&Qbuf[(nb << 4) + c][quad << 3];

    const int tb = w >> 1, half = w & 1;
    float lsr[4] = {0.f, 0.f, 0.f, 0.f};
    f32x4 oacc[4][2] = {};

    for (int i = 0; i < 15; ++i) {
        const int pb = i & 1;
        if (i < 14) stage(i + 1, pb ^ 1);

        // ---- S: wave's 32 keys x all 64 q ----
        const unsigned short* Kp = &KV[pb][(tb << 11) + (quad << 9) + (((half << 5) + c) << 3)];
        short8 ka0 = *(const short8*)(Kp);
        short8 ka1 = *(const short8*)(Kp + 128);
        f32x4 s0[4], s1[4];
        #pragma unroll
        for (int nb = 0; nb < 4; ++nb) s0[nb] = MFMA16(ka0, qf[nb], zero);
        #pragma unroll
        for (int nb = 0; nb < 4; ++nb) s1[nb] = MFMA16(ka1, qf[nb], zero);

        // ---- exp2 + in-register pack (sigma order) ----
        U8 af[4];
        #pragma unroll
        for (int nb = 0; nb < 4; ++nb) {
            float p0 = EXP2(s0[nb][0]), p1 = EXP2(s0[nb][1]);
            float p2 = EXP2(s0[nb][2]), p3 = EXP2(s0[nb][3]);
            float q0 = EXP2(s1[nb][0]), q1 = EXP2(s1[nb][1]);
            float q2 = EXP2(s1[nb][2]), q3 = EXP2(s1[nb][3]);
            lsr[nb] += ((p0 + p1) + (p2 + p3)) + ((q0 + q1) + (q2 + q3));
            af[nb].u = make_uint4(pk2bf(p0, p1), pk2bf(p2, p3),
                                  pk2bf(q0, q1), pk2bf(q2, q3));
        }

        // ---- PV: partial O over wave's keys ----
        const unsigned short* Vp = &KV[pb][4096 + (tb << 11) + (half << 10) + (quad << 7) + (c << 3)];
        short8 vb0 = *(const short8*)(Vp);
        short8 vb1 = *(const short8*)(Vp + 512);
        #pragma unroll
        for (int nb = 0; nb < 4; ++nb) {
            oacc[nb][0] = MFMA16(af[nb].s, vb0, oacc[nb][0]);
            oacc[nb][1] = MFMA16(af[nb].s, vb1, oacc[nb][1]);
        }

        __syncthreads();
    }

    // ---- cross-wave reduction (once per block) ----
    #pragma unroll
    for (int nb = 0; nb < 4; ++nb) {
        lsr[nb] += __shfl_xor(lsr[nb], 16);
        lsr[nb] += __shfl_xor(lsr[nb], 32);
    }
    if (lane < 16) {
        #pragma unroll
        for (int nb = 0; nb < 4; ++nb) lsumLDS[w][(nb << 4) + lane] = lsr[nb];
    }
    float* Op = (float*)&KV[0][0];   // 8192 floats = the staging LDS
    #pragma unroll
    for (int nb = 0; nb < 4; ++nb)
        #pragma unroll
        for (int db = 0; db < 2; ++db)
            *(f32x4*)&Op[((((w << 2) + nb) << 1) + db) * 256 + (c << 4) + (quad << 2)] =
                oacc[nb][db];
    __syncthreads();

    // wave w reduces q-block nb=w; lane holds q_in = 4*quad+r, d = 16*db+c
    f32x4 lt = {0.f, 0.f, 0.f, 0.f};
    #pragma unroll
    for (int w2 = 0; w2 < 4; ++w2)
        lt += *(f32x4*)&lsumLDS[w2][(w << 4) + (quad << 2)];
    float inv[4];
    #pragma unroll
    for (int r = 0; r < 4; ++r) inv[r] = 1.0f / (lt[r] - 64.0f);   // pad correction
    #pragma unroll
    for (int db = 0; db < 2; ++db) {
        f32x4 o = zero;
        #pragma unroll
        for (int w2 = 0; w2 < 4; ++w2)
            o += *(f32x4*)&Op[((((w2 << 2) + w) << 1) + db) * 256 + (c << 4) + (quad << 2)];
        #pragma unroll
        for (int r = 0; r < 4; ++r) {
            const int row = qoff + (w << 4) + (quad << 2) + r;
            ob[(size_t)row * DIM + h * HD + (db << 4) + c] = f2bf(o[r] * inv[r]);
        }
    }
}

// ---------------------------------------------------------------------------
// Output projection (x + y), 128x64 tiles, fp32 out + bias. 328 flat blocks.
// ---------------------------------------------------------------------------
__global__ __launch_bounds__(256) void proj_mfma(
    const unsigned short* __restrict__ obx, const unsigned short* __restrict__ oby,
    const unsigned short* __restrict__ projT, const float* __restrict__ bias,
    float* __restrict__ outx, float* __restrict__ outy)
{
    __shared__ __align__(16) unsigned short At[128][32];
    __shared__ __align__(16) unsigned short Btile[64][32];
    const int tid = threadIdx.x;
    const int lane = tid & 63, w = tid >> 6;
    const int c = lane & 15, quad = lane >> 4;

    const int bid = blockIdx.x;
    const int n0 = (bid & 3) << 6, mg = (bid >> 2) << 7;   // 128-row tiles
    const unsigned short* Ab = (mg < 6400) ? obx + (size_t)mg * 256
                                           : oby + (size_t)(mg - 6400) * 256;
    float* Cf = (mg < 6400) ? outx + (size_t)mg * 256 : outy + (size_t)(mg - 6400) * 256;

    // A staging: thread t -> row t>>1, 16-elem chunk (t&1); 32B contiguous
    const int arow = tid >> 1, ach = (tid & 1) << 4;
    const unsigned short* Ap = Ab + (size_t)arow * 256 + ach;
    const int brow = tid >> 2, bch = (tid & 3) << 3;
    const unsigned short* Bp = projT + (size_t)(n0 + brow) * 256 + bch;

    uint4 an0 = *(const uint4*)Ap, an1 = *(const uint4*)(Ap + 8);
    uint4 bn  = *(const uint4*)Bp;
    f32x4 acc[2][4] = {};
    for (int k0 = 0; k0 < 256; k0 += 32) {
        *(uint4*)&At[arow][ach]     = an0;
        *(uint4*)&At[arow][ach + 8] = an1;
        *(uint4*)&Btile[brow][bch]  = bn;
        if (k0 < 224) {
            an0 = *(const uint4*)(Ap + k0 + 32);
            an1 = *(const uint4*)(Ap + k0 + 40);
            bn  = *(const uint4*)(Bp + k0 + 32);
        }
        __syncthreads();
        #pragma unroll
        for (int ml = 0; ml < 2; ++ml) {
            short8 a = *(short8*)&At[(w << 5) + (ml << 4) + c][quad << 3];
            #pragma unroll
            for (int nb = 0; nb < 4; ++nb) {
                short8 b = *(short8*)&Btile[(nb << 4) + c][quad << 3];
                acc[ml][nb] = MFMA16(a, b, acc[ml][nb]);
            }
        }
        __syncthreads();
    }
    #pragma unroll
    for (int ml = 0; ml < 2; ++ml) {
        const int rl = (w << 5) + (ml << 4) + (quad << 2);
        #pragma unroll
        for (int nb = 0; nb < 4; ++nb) {
            const int col = n0 + (nb << 4) + c;
            const float bv = bias[col];
            #pragma unroll
            for (int r = 0; r < 4; ++r)
                Cf[(size_t)(rl + r) * 256 + col] = acc[ml][nb][r] + bv;
        }
    }
}

// ---------------------------------------------------------------------------
extern "C" void kernel_launch(void* const* d_in, const int* in_sizes, int n_in,
                              void* d_out, int out_size, void* d_ws, size_t ws_size,
                              hipStream_t stream)
{
    const float* x      = (const float*)d_in[0];
    const float* y      = (const float*)d_in[1];
    const float* Wq     = (const float*)d_in[2];
    const float* Wkv    = (const float*)d_in[3];
    const float* sr_w   = (const float*)d_in[4];
    const float* sr_b   = (const float*)d_in[5];
    const float* ln_g   = (const float*)d_in[6];
    const float* ln_b   = (const float*)d_in[7];
    const float* proj_w = (const float*)d_in[8];
    const float* proj_b = (const float*)d_in[9];

    unsigned short* p = (unsigned short*)d_ws;
    unsigned short* WqT   = p;  p += 65536;
    unsigned short* WkvT  = p;  p += 131072;
    unsigned short* projT = p;  p += 65536;
    unsigned short* BwT   = p;  p += 262144;
    unsigned short* redx  = p;  p += 409600;     // 1600x256 (conv out, pre-LN)
    unsigned short* redy  = p;  p += 262144;     // 1024x256
    unsigned short* obx   = p;  p += 1638400;    // attn out x (bf16)
    unsigned short* oby   = p;  p += 1048576;    // attn out y
    unsigned short* kswx  = p;  p += 409600;     // K_x swizzled [h][25 tiles][2048]
    unsigned short* vswx  = p;  p += 409600;     // V_x swizzled (sigma) [h][25][2048]
    unsigned short* kswy  = p;  p += 262144;     // [b][h][4][2048]
    unsigned short* vswy  = p;  p += 262144;
    unsigned short* kmsw  = p;  p += 65536;      // mean K_y swizzled [h][4][2048]
    unsigned short* vmsw  = p;  p += 65536;
    unsigned short* kpad  = p;  p += 2048;       // zero pad tile (K)
    unsigned short* vpad  = p;  p += 2048;       // zero pad tile (V), contiguous
    float* outx = (float*)d_out;
    float* outy = outx + 6400 * 256;

    prep_w<<<2064, 256, 0, stream>>>(Wq, Wkv, proj_w, sr_w, WqT, WkvT, projT, BwT, kpad);
    conv_kernel<<<164, 256, 0, stream>>>(x, y, BwT, sr_b, redx, redy);
    kvln_kernel<<<328, 256, 0, stream>>>(redx, redy, WkvT, ln_g, ln_b,
                                         kswx, vswx, kswy, vswy);
    kvmean_kernel<<<512, 256, 0, stream>>>(kswy, vswy, kmsw, vmsw);
    attn_mfma<<<1312, 256, 0, stream>>>(x, y, WqT, obx, oby, kswx, vswx,
                                        kmsw, vmsw, kswy, vswy, kpad, vpad);
    proj_mfma<<<328, 256, 0, stream>>>(obx, oby, projT, proj_b, outx, outy);
}

// Round 10
// 166.561 us; speedup vs baseline: 1.0753x; 1.0753x over previous
//
#include <hip/hip_runtime.h>
#include <math.h>

#define DIM 256
#define HD 32
#define KSCALE (0.17677669529663687f * 1.44269504088896340736f)  /* SCALE*log2(e) */
#define EPS 1e-5f

typedef __attribute__((ext_vector_type(8))) short short8;   // 8 bf16 = 4 VGPRs
typedef __attribute__((ext_vector_type(4))) float f32x4;

union U8 { uint4 u; short8 s; };

__device__ inline unsigned short f2bf(float f) {
    union { float f; unsigned u; } v; v.f = f;
    unsigned r = v.u + 0x7FFF + ((v.u >> 16) & 1);   // RNE
    return (unsigned short)(r >> 16);
}
__device__ inline float bf2f(unsigned short h) {
    union { unsigned u; float f; } v; v.u = ((unsigned)h) << 16;
    return v.f;
}
// pack two fp32 -> two bf16 (round-half-up) in one dword: 3 VALU ops
__device__ inline unsigned pk2bf(float a, float b) {
    unsigned ua = __float_as_uint(a) + 0x8000u;
    unsigned ub = __float_as_uint(b) + 0x8000u;
    return __builtin_amdgcn_perm(ub, ua, 0x07060302u);  // {low=bf(a), high=bf(b)}
}
__device__ inline uint4 pk8bf(float4 a, float4 b) {
    return make_uint4(pk2bf(a.x, a.y), pk2bf(a.z, a.w),
                      pk2bf(b.x, b.y), pk2bf(b.z, b.w));
}
// unpack bf16x2 dword -> 2 fp32
__device__ inline void up2(unsigned u, float& a, float& b) {
    a = __uint_as_float(u << 16);
    b = __uint_as_float(u & 0xffff0000u);
}
// async global->LDS DMA, 16B/lane; lds dest = wave-uniform base + lane*16
__device__ inline void gl_lds16(const unsigned short* g, unsigned short* l) {
    __builtin_amdgcn_global_load_lds(
        (const __attribute__((address_space(1))) unsigned int*)g,
        (__attribute__((address_space(3))) unsigned int*)l, 16, 0, 0);
}
#define MFMA16(a, b, c) __builtin_amdgcn_mfma_f32_16x16x32_bf16(a, b, c, 0, 0, 0)
#define EXP2(x) __builtin_amdgcn_exp2f(x)

// ---------------------------------------------------------------------------
// Weights prep: transposed bf16 WqT/WkvT/projT [N][K], conv BwT[o][q*256+i],
// plus zero-fill of the attention pad tiles (4096 elems). Grid 2064 x 256.
// ---------------------------------------------------------------------------
__global__ __launch_bounds__(256) void prep_w(
    const float* __restrict__ Wq, const float* __restrict__ Wkv,
    const float* __restrict__ projw, const float* __restrict__ srw,
    unsigned short* __restrict__ WqT, unsigned short* __restrict__ WkvT,
    unsigned short* __restrict__ projT, unsigned short* __restrict__ BwT,
    unsigned short* __restrict__ pads)
{
    int idx = blockIdx.x * 256 + threadIdx.x;
    if (idx < 65536) { int n = idx >> 8, k = idx & 255; WqT[idx] = f2bf(Wq[(k << 8) + n]); return; }
    idx -= 65536;
    if (idx < 131072) { int n = idx >> 8, k = idx & 255; WkvT[idx] = f2bf(Wkv[(k << 9) + n]); return; }
    idx -= 131072;
    if (idx < 65536) { int n = idx >> 8, k = idx & 255; projT[idx] = f2bf(projw[(k << 8) + n]); return; }
    idx -= 65536;
    if (idx < 262144) { int o = idx >> 10, rem = idx & 1023, q = rem >> 8, i = rem & 255;
                        BwT[idx] = f2bf(srw[(o << 10) + (i << 2) + q]); return; }
    idx -= 262144;
    pads[idx] = 0;   // kpad+vpad (4096 elems)
}

// ---------------------------------------------------------------------------
// Merged conv + q-projection. Grid 656 flat blocks:
//   bid < 328: split-K conv (K-half kh of 1024): r = bid>>2:
//       r<50: x (tile r>>1, kh=r&1); else y (idx=(r-50)>>1 -> b,mt; kh=(r-50)&1).
//     Writes UN-biased bf16 partials to redA (kh=0) / redB (kh=1), rows
//     [x 0..1600) then [y b*256+...], cols n0..n0+64.
//   bid >= 328: q-projection, 128x64 tiles (8 MFMA/wave/k-iter), A staged
//     from fp32 with in-register bf16 pack. mg = tile*128 over 10496 rows.
// ---------------------------------------------------------------------------
__global__ __launch_bounds__(256) void convq_kernel(
    const float* __restrict__ x, const float* __restrict__ y,
    const unsigned short* __restrict__ BwT, const unsigned short* __restrict__ WqT,
    unsigned short* __restrict__ redA, unsigned short* __restrict__ redB,
    unsigned short* __restrict__ qxb, unsigned short* __restrict__ qyb)
{
    __shared__ __align__(16) unsigned short At[128][32];
    __shared__ __align__(16) unsigned short Btile[64][32];
    const int tid = threadIdx.x;
    const int lane = tid & 63, w = tid >> 6;
    const int c = lane & 15, quad = lane >> 4;
    const int bid = blockIdx.x;

    if (bid < 328) {
        // ---------------- split-K conv path ----------------
        const int n0 = (bid & 3) << 6, r = bid >> 2;
        const float* Xb; int W, W2, m0g, pl, kh;
        if (r < 50) {
            const int myi = r >> 1; kh = r & 1;
            Xb = x; W = 80; W2 = 40; m0g = myi * 64; pl = myi * 64;
        } else {
            const int ry = r - 50, idx = ry >> 1; kh = ry & 1;
            const int b = idx >> 2, mt = idx & 3;
            Xb = y + (size_t)b * 262144; W = 32; W2 = 16;
            m0g = 1600 + b * 256 + mt * 64; pl = mt * 64;
        }
        unsigned short* Cb = (kh == 0) ? redA : redB;
        const int srow = tid >> 2, sch = (tid & 3) << 3;
        const int p = pl + srow;
        const int oy = p / W2, ox = p - oy * W2;
        const unsigned short* Bp = BwT + (size_t)(n0 + srow) * 1024 + sch;
        const int kbeg = kh << 9, kend = kbeg + 512;

        auto addrA = [&](int k0) {
            const int qq = k0 >> 8;
            const int rrow = (2 * oy + (qq >> 1)) * W + 2 * ox + (qq & 1);
            return Xb + (size_t)rrow * DIM + (k0 & 255) + sch;
        };

        const float* ap = addrA(kbeg);
        float4 a0 = *(const float4*)ap, a1 = *(const float4*)(ap + 4);
        uint4 bn = *(const uint4*)(Bp + kbeg);
        f32x4 acc[4] = {};
        for (int k0 = kbeg; k0 < kend; k0 += 32) {
            *(uint4*)&At[srow][sch]    = pk8bf(a0, a1);
            *(uint4*)&Btile[srow][sch] = bn;
            if (k0 < kend - 32) {
                const float* np = addrA(k0 + 32);
                a0 = *(const float4*)np; a1 = *(const float4*)(np + 4);
                bn = *(const uint4*)(Bp + k0 + 32);
            }
            __syncthreads();
            short8 a = *(short8*)&At[(w << 4) + c][quad << 3];
            #pragma unroll
            for (int nb = 0; nb < 4; ++nb) {
                short8 b = *(short8*)&Btile[(nb << 4) + c][quad << 3];
                acc[nb] = MFMA16(a, b, acc[nb]);
            }
            __syncthreads();
        }
        const int rl = (w << 4) + (quad << 2);
        #pragma unroll
        for (int nb = 0; nb < 4; ++nb) {
            const int col = n0 + (nb << 4) + c;
            #pragma unroll
            for (int rr = 0; rr < 4; ++rr)
                Cb[(size_t)(m0g + rl + rr) * DIM + col] = f2bf(acc[nb][rr]);
        }
    } else {
        // ---------------- q-projection path (128x64 tile) ----------------
        const int r = bid - 328;
        const int n0 = (r & 3) << 6, mg = (r >> 2) << 7;
        const float* Ab = (mg < 6400) ? x + (size_t)mg * 256
                                      : y + (size_t)(mg - 6400) * 256;
        unsigned short* Cb = (mg < 6400) ? qxb + (size_t)mg * 256
                                         : qyb + (size_t)(mg - 6400) * 256;
        const int arow = tid >> 1, ach = (tid & 1) << 4;   // 16 fp32/thread
        const float* Ap = Ab + (size_t)arow * 256 + ach;
        const int brow = tid >> 2, bch = (tid & 3) << 3;
        const unsigned short* Bp = WqT + (size_t)(n0 + brow) * 256 + bch;

        float4 a0 = *(const float4*)Ap,       a1 = *(const float4*)(Ap + 4);
        float4 a2 = *(const float4*)(Ap + 8), a3 = *(const float4*)(Ap + 12);
        uint4 bn = *(const uint4*)Bp;
        f32x4 acc[2][4] = {};
        for (int k0 = 0; k0 < 256; k0 += 32) {
            *(uint4*)&At[arow][ach]     = pk8bf(a0, a1);
            *(uint4*)&At[arow][ach + 8] = pk8bf(a2, a3);
            *(uint4*)&Btile[brow][bch]  = bn;
            if (k0 < 224) {
                a0 = *(const float4*)(Ap + k0 + 32); a1 = *(const float4*)(Ap + k0 + 36);
                a2 = *(const float4*)(Ap + k0 + 40); a3 = *(const float4*)(Ap + k0 + 44);
                bn = *(const uint4*)(Bp + k0 + 32);
            }
            __syncthreads();
            #pragma unroll
            for (int ml = 0; ml < 2; ++ml) {
                short8 a = *(short8*)&At[(w << 5) + (ml << 4) + c][quad << 3];
                #pragma unroll
                for (int nb = 0; nb < 4; ++nb) {
                    short8 b = *(short8*)&Btile[(nb << 4) + c][quad << 3];
                    acc[ml][nb] = MFMA16(a, b, acc[ml][nb]);
                }
            }
            __syncthreads();
        }
        #pragma unroll
        for (int ml = 0; ml < 2; ++ml) {
            const int rl = (w << 5) + (ml << 4) + (quad << 2);
            #pragma unroll
            for (int nb = 0; nb < 4; ++nb) {
                const int col = n0 + (nb << 4) + c;
                #pragma unroll
                for (int rr = 0; rr < 4; ++rr)
                    Cb[(size_t)(rl + rr) * 256 + col] = f2bf(acc[ml][nb][rr]);
            }
        }
    }
}

// ---------------------------------------------------------------------------
// KV projection with fused conv split-K reduce (redA+redB+bias) and fused
// LayerNorm on A-rows. Outputs in attention's swizzled per-(head, 64-key-
// tile) 4KB layouts:
//   K: ksw[h][tile][(d>>3)*64 + key]*8 + (d&7)          (pre-scaled by KSCALE)
//   V: vsw[h][tile][ half*1024 + (d>>4)*512 + ((kl>>2)&3)*128 + (d&15)*8
//                    + (kl>>4)*4 + (kl&3) ],  half=key>>5, kl=key&31
// ---------------------------------------------------------------------------
__global__ __launch_bounds__(256) void kvln_kernel(
    const unsigned short* __restrict__ redA, const unsigned short* __restrict__ redB,
    const unsigned short* __restrict__ WkvT, const float* __restrict__ srb,
    const float* __restrict__ g, const float* __restrict__ bta,
    unsigned short* __restrict__ kswx, unsigned short* __restrict__ vswx,
    unsigned short* __restrict__ kswy, unsigned short* __restrict__ vswy)
{
    __shared__ __align__(16) unsigned short At[64][32];
    __shared__ __align__(16) unsigned short Btile[64][32];
    const int tid = threadIdx.x;
    const int lane = tid & 63, w = tid >> 6;
    const int c = lane & 15, quad = lane >> 4;
    const int srow = tid >> 2, sch = (tid & 3) << 3;
    const int bid = blockIdx.x;
    const int n0 = (bid & 7) << 6, mg = (bid >> 3) << 6;
    const unsigned short* ArowA = redA + (size_t)(mg + srow) * 256 + sch;
    const unsigned short* ArowB = redB + (size_t)(mg + srow) * 256 + sch;

    // ---- sum split-K partials + bias; row stats ----
    uint4 araw[8];
    float s1 = 0.f, s2 = 0.f;
    #pragma unroll
    for (int ci = 0; ci < 8; ++ci) {
        uint4 ua = *(const uint4*)(ArowA + (ci << 5));
        uint4 ub = *(const uint4*)(ArowB + (ci << 5));
        const int ch = (ci << 5) + sch;
        float4 sb0 = *(const float4*)(srb + ch), sb1 = *(const float4*)(srb + ch + 4);
        const unsigned* dua = (const unsigned*)&ua;
        const unsigned* dub = (const unsigned*)&ub;
        float t[8];
        #pragma unroll
        for (int dd = 0; dd < 4; ++dd) {
            float a0, a1, b0, b1;
            up2(dua[dd], a0, a1); up2(dub[dd], b0, b1);
            t[2 * dd]     = a0 + b0;
            t[2 * dd + 1] = a1 + b1;
        }
        t[0] += sb0.x; t[1] += sb0.y; t[2] += sb0.z; t[3] += sb0.w;
        t[4] += sb1.x; t[5] += sb1.y; t[6] += sb1.z; t[7] += sb1.w;
        #pragma unroll
        for (int j = 0; j < 8; ++j) { s1 += t[j]; s2 += t[j] * t[j]; }
        araw[ci] = pk8bf(make_float4(t[0], t[1], t[2], t[3]),
                         make_float4(t[4], t[5], t[6], t[7]));
    }
    s1 += __shfl_xor(s1, 1); s1 += __shfl_xor(s1, 2);
    s2 += __shfl_xor(s2, 1); s2 += __shfl_xor(s2, 2);
    const float mean = s1 * (1.0f / 256.0f);
    const float var  = s2 * (1.0f / 256.0f) - mean * mean;
    const float rstd = rsqrtf(var + EPS);

    // ---- apply LN, repack to bf16 ----
    #pragma unroll
    for (int ci = 0; ci < 8; ++ci) {
        const int ch = (ci << 5) + sch;
        float4 g0 = *(const float4*)(g + ch),   g1 = *(const float4*)(g + ch + 4);
        float4 b0 = *(const float4*)(bta + ch), b1 = *(const float4*)(bta + ch + 4);
        const unsigned* du = (const unsigned*)&araw[ci];
        float v[8];
        #pragma unroll
        for (int dd = 0; dd < 4; ++dd) up2(du[dd], v[2 * dd], v[2 * dd + 1]);
        float4 o0 = make_float4(fmaf((v[0] - mean) * rstd, g0.x, b0.x),
                                fmaf((v[1] - mean) * rstd, g0.y, b0.y),
                                fmaf((v[2] - mean) * rstd, g0.z, b0.z),
                                fmaf((v[3] - mean) * rstd, g0.w, b0.w));
        float4 o1 = make_float4(fmaf((v[4] - mean) * rstd, g1.x, b1.x),
                                fmaf((v[5] - mean) * rstd, g1.y, b1.y),
                                fmaf((v[6] - mean) * rstd, g1.z, b1.z),
                                fmaf((v[7] - mean) * rstd, g1.w, b1.w));
        araw[ci] = pk8bf(o0, o1);
    }

    // ---- GEMM k-loop ----
    const unsigned short* Bp = WkvT + (size_t)(n0 + srow) * 256 + sch;
    uint4 bn = *(const uint4*)Bp;
    f32x4 acc[4] = {};
    for (int k0 = 0; k0 < 256; k0 += 32) {
        *(uint4*)&At[srow][sch]    = araw[k0 >> 5];
        *(uint4*)&Btile[srow][sch] = bn;
        if (k0 < 224) bn = *(const uint4*)(Bp + k0 + 32);
        __syncthreads();
        short8 a = *(short8*)&At[(w << 4) + c][quad << 3];
        #pragma unroll
        for (int nb = 0; nb < 4; ++nb) {
            short8 b = *(short8*)&Btile[(nb << 4) + c][quad << 3];
            acc[nb] = MFMA16(a, b, acc[nb]);
        }
        __syncthreads();
    }

    const int rl = (w << 4) + (quad << 2);        // first of 4 key rows (in-tile)
    const int r0 = mg - 1600;                     // y row offset (if y)
    const int half = rl >> 5, kl0 = rl & 31;
    const int vkeyoff = (half << 10) + (((kl0 >> 2) & 3) << 7) + ((kl0 >> 4) << 2);
    #pragma unroll
    for (int nb = 0; nb < 4; ++nb) {
        const int col = n0 + (nb << 4) + c;
        if (col < 256) {
            const int hh = col >> 5, d = col & 31;
            unsigned short* base = (mg < 1600)
                ? kswx + ((size_t)(hh * 25 + (mg >> 6)) << 11)
                : kswy + ((size_t)(r0 >> 8) << 16) + ((size_t)((hh << 2) + ((r0 >> 6) & 3)) << 11);
            unsigned short* dst = base + (((d >> 3) << 9)) + (d & 7);
            #pragma unroll
            for (int r = 0; r < 4; ++r)
                dst[(rl + r) << 3] = f2bf(acc[nb][r] * KSCALE);
        } else {
            const int hd = col - 256, hv = hd >> 5, d = hd & 31;
            unsigned short* base = (mg < 1600)
                ? vswx + ((size_t)(hv * 25 + (mg >> 6)) << 11)
                : vswy + ((size_t)(r0 >> 8) << 16) + ((size_t)((hv << 2) + ((r0 >> 6) & 3)) << 11);
            unsigned lo = (unsigned)f2bf(acc[nb][0]) | ((unsigned)f2bf(acc[nb][1]) << 16);
            unsigned hi = (unsigned)f2bf(acc[nb][2]) | ((unsigned)f2bf(acc[nb][3]) << 16);
            *(uint2*)(base + vkeyoff + ((d >> 4) << 9) + ((d & 15) << 3)) =
                make_uint2(lo, hi);
        }
    }
}

// ---------------------------------------------------------------------------
// Batch-mean of support KV in swizzled layout (elementwise; layout-agnostic).
// ---------------------------------------------------------------------------
__global__ __launch_bounds__(256) void kvmean_kernel(
    const unsigned short* __restrict__ kswy, const unsigned short* __restrict__ vswy,
    unsigned short* __restrict__ kmsw, unsigned short* __restrict__ vmsw)
{
    int idx = blockIdx.x * 256 + threadIdx.x;
    const unsigned short* s; unsigned short* dv; int e;
    if (idx < 65536) { s = kswy; dv = kmsw; e = idx; }
    else             { s = vswy; dv = vmsw; e = idx - 65536; }
    float sm = bf2f(s[e]) + bf2f(s[e + 65536]) + bf2f(s[e + 131072]) + bf2f(s[e + 196608]);
    dv[e] = f2bf(0.25f * sm);
}

// ---------------------------------------------------------------------------
// MFMA flash attention (r8 structure), key-split waves: 128-key double-tile
// per iteration, wave w owns keys [32w,32w+32): 8 S-MFMAs + 8 PV-MFMAs into
// a partial O[64q][32d]; one barrier per double-tile; in-register sigma-
// packed P. Tiles 0..24 kswx, 25..28 mean/y, 29 = zero pad (subtract 64 from
// denominators). In-place on qxb/qyb. Grid 1312 flat blocks.
// ---------------------------------------------------------------------------
__global__ __launch_bounds__(256) void attn_mfma(
    unsigned short* __restrict__ qxb, unsigned short* __restrict__ qyb,
    const unsigned short* __restrict__ kswx, const unsigned short* __restrict__ vswx,
    const unsigned short* __restrict__ kmsw, const unsigned short* __restrict__ vmsw,
    const unsigned short* __restrict__ kswy, const unsigned short* __restrict__ vswy,
    const unsigned short* __restrict__ kpad, const unsigned short* __restrict__ vpad)
{
    __shared__ __align__(16) unsigned short KV[2][8192];  // [buf][K0 K1 V0 V1]
    __shared__ __align__(16) float lsumLDS[4][64];

    const int tid = threadIdx.x;
    const int lane = tid & 63, w = tid >> 6;
    const int c = lane & 15, quad = lane >> 4;

    const int bid = blockIdx.x;
    unsigned short* qb; const unsigned short *k1, *v1, *k2, *v2;
    int h, qoff;
    if (bid < 800) {
        h = bid / 100; qoff = (bid - h * 100) * 64;
        qb = qxb;
        k1 = kswx + ((size_t)h * 25 << 11); v1 = vswx + ((size_t)h * 25 << 11);
        k2 = kmsw + ((size_t)h << 13);      v2 = vmsw + ((size_t)h << 13);
    } else {
        const int idx = bid - 800, b = idx >> 7, rem = idx & 127;
        h = rem >> 4; qoff = b * 1024 + (rem & 15) * 64;
        qb = qyb;
        k1 = kswx + ((size_t)h * 25 << 11); v1 = vswx + ((size_t)h * 25 << 11);
        k2 = kswy + ((size_t)b << 16) + ((size_t)h << 13);
        v2 = vswy + ((size_t)b << 16) + ((size_t)h << 13);
    }

    // loop-invariant Q fragments for all 4 q-blocks (B-operand of S)
    short8 qf[4];
    #pragma unroll
    for (int nb = 0; nb < 4; ++nb)
        qf[nb] = *(const short8*)(qb + (size_t)(qoff + (nb << 4) + c) * DIM
                                  + h * HD + (quad << 3));

    auto ksrc = [&](int t) -> const unsigned short* {
        if (t < 25) return k1 + (t << 11);
        if (t < 29) return k2 + ((t - 25) << 11);
        return kpad;
    };
    auto vsrc = [&](int t) -> const unsigned short* {
        if (t < 25) return v1 + (t << 11);
        if (t < 29) return v2 + ((t - 25) << 11);
        return vpad;
    };

    const int sg = (w << 9) + (lane << 3);   // wave's staged quarter + lane chunk
    auto stage = [&](int i, int pb) {        // stage tiles 2i, 2i+1
        #pragma unroll
        for (int tt = 0; tt < 2; ++tt) {
            const int t = 2 * i + tt;
            gl_lds16(ksrc(t) + sg, &KV[pb][(tt << 11) + (w << 9)]);
            gl_lds16(vsrc(t) + sg, &KV[pb][4096 + (tt << 11) + (w << 9)]);
        }
    };

    const int tb = w >> 1, half = w & 1;
    float lsr[4] = {0.f, 0.f, 0.f, 0.f};
    f32x4 oacc[4][2] = {};
    const f32x4 zero = {0.f, 0.f, 0.f, 0.f};

    stage(0, 0);
    __syncthreads();

    for (int i = 0; i < 15; ++i) {
        const int pb = i & 1;
        if (i < 14) stage(i + 1, pb ^ 1);

        // ---- S: wave's 32 keys x all 64 q ----
        const unsigned short* Kp = &KV[pb][(tb << 11) + (quad << 9) + (((half << 5) + c) << 3)];
        short8 ka0 = *(const short8*)(Kp);
        short8 ka1 = *(const short8*)(Kp + 128);
        f32x4 s0[4], s1[4];
        #pragma unroll
        for (int nb = 0; nb < 4; ++nb) s0[nb] = MFMA16(ka0, qf[nb], zero);
        #pragma unroll
        for (int nb = 0; nb < 4; ++nb) s1[nb] = MFMA16(ka1, qf[nb], zero);

        // ---- exp2 + in-register pack (sigma order) ----
        U8 af[4];
        #pragma unroll
        for (int nb = 0; nb < 4; ++nb) {
            float p0 = EXP2(s0[nb][0]), p1 = EXP2(s0[nb][1]);
            float p2 = EXP2(s0[nb][2]), p3 = EXP2(s0[nb][3]);
            float q0 = EXP2(s1[nb][0]), q1 = EXP2(s1[nb][1]);
            float q2 = EXP2(s1[nb][2]), q3 = EXP2(s1[nb][3]);
            lsr[nb] += ((p0 + p1) + (p2 + p3)) + ((q0 + q1) + (q2 + q3));
            af[nb].u = make_uint4(pk2bf(p0, p1), pk2bf(p2, p3),
                                  pk2bf(q0, q1), pk2bf(q2, q3));
        }

        // ---- PV: partial O over wave's keys ----
        const unsigned short* Vp = &KV[pb][4096 + (tb << 11) + (half << 10) + (quad << 7) + (c << 3)];
        short8 vb0 = *(const short8*)(Vp);
        short8 vb1 = *(const short8*)(Vp + 512);
        #pragma unroll
        for (int nb = 0; nb < 4; ++nb) {
            oacc[nb][0] = MFMA16(af[nb].s, vb0, oacc[nb][0]);
            oacc[nb][1] = MFMA16(af[nb].s, vb1, oacc[nb][1]);
        }

        __syncthreads();
    }

    // ---- cross-wave reduction (once per block) ----
    #pragma unroll
    for (int nb = 0; nb < 4; ++nb) {
        lsr[nb] += __shfl_xor(lsr[nb], 16);
        lsr[nb] += __shfl_xor(lsr[nb], 32);
    }
    if (lane < 16) {
        #pragma unroll
        for (int nb = 0; nb < 4; ++nb) lsumLDS[w][(nb << 4) + lane] = lsr[nb];
    }
    float* Op = (float*)&KV[0][0];   // 8192 floats = the staging LDS
    #pragma unroll
    for (int nb = 0; nb < 4; ++nb)
        #pragma unroll
        for (int db = 0; db < 2; ++db)
            *(f32x4*)&Op[((((w << 2) + nb) << 1) + db) * 256 + (c << 4) + (quad << 2)] =
                oacc[nb][db];
    __syncthreads();

    // wave w reduces q-block nb=w; lane holds q_in = 4*quad+r, d = 16*db+c
    f32x4 lt = {0.f, 0.f, 0.f, 0.f};
    #pragma unroll
    for (int w2 = 0; w2 < 4; ++w2)
        lt += *(f32x4*)&lsumLDS[w2][(w << 4) + (quad << 2)];
    float inv[4];
    #pragma unroll
    for (int r = 0; r < 4; ++r) inv[r] = 1.0f / (lt[r] - 64.0f);   // pad correction
    #pragma unroll
    for (int db = 0; db < 2; ++db) {
        f32x4 o = zero;
        #pragma unroll
        for (int w2 = 0; w2 < 4; ++w2)
            o += *(f32x4*)&Op[((((w2 << 2) + w) << 1) + db) * 256 + (c << 4) + (quad << 2)];
        #pragma unroll
        for (int r = 0; r < 4; ++r) {
            const int row = qoff + (w << 4) + (quad << 2) + r;
            qb[(size_t)row * DIM + h * HD + (db << 4) + c] = f2bf(o[r] * inv[r]);
        }
    }
}

// ---------------------------------------------------------------------------
// Output projection (x + y), 128x64 tiles, fp32 out + bias. 328 flat blocks.
// ---------------------------------------------------------------------------
__global__ __launch_bounds__(256) void proj_mfma(
    const unsigned short* __restrict__ qxb, const unsigned short* __restrict__ qyb,
    const unsigned short* __restrict__ projT, const float* __restrict__ bias,
    float* __restrict__ outx, float* __restrict__ outy)
{
    __shared__ __align__(16) unsigned short At[128][32];
    __shared__ __align__(16) unsigned short Btile[64][32];
    const int tid = threadIdx.x;
    const int lane = tid & 63, w = tid >> 6;
    const int c = lane & 15, quad = lane >> 4;

    const int bid = blockIdx.x;
    const int n0 = (bid & 3) << 6, mg = (bid >> 2) << 7;   // 128-row tiles
    const unsigned short* Ab = (mg < 6400) ? qxb + (size_t)mg * 256
                                           : qyb + (size_t)(mg - 6400) * 256;
    float* Cf = (mg < 6400) ? outx + (size_t)mg * 256 : outy + (size_t)(mg - 6400) * 256;

    const int arow = tid >> 1, ach = (tid & 1) << 4;
    const unsigned short* Ap = Ab + (size_t)arow * 256 + ach;
    const int brow = tid >> 2, bch = (tid & 3) << 3;
    const unsigned short* Bp = projT + (size_t)(n0 + brow) * 256 + bch;

    uint4 an0 = *(const uint4*)Ap, an1 = *(const uint4*)(Ap + 8);
    uint4 bn  = *(const uint4*)Bp;
    f32x4 acc[2][4] = {};
    for (int k0 = 0; k0 < 256; k0 += 32) {
        *(uint4*)&At[arow][ach]     = an0;
        *(uint4*)&At[arow][ach + 8] = an1;
        *(uint4*)&Btile[brow][bch]  = bn;
        if (k0 < 224) {
            an0 = *(const uint4*)(Ap + k0 + 32);
            an1 = *(const uint4*)(Ap + k0 + 40);
            bn  = *(const uint4*)(Bp + k0 + 32);
        }
        __syncthreads();
        #pragma unroll
        for (int ml = 0; ml < 2; ++ml) {
            short8 a = *(short8*)&At[(w << 5) + (ml << 4) + c][quad << 3];
            #pragma unroll
            for (int nb = 0; nb < 4; ++nb) {
                short8 b = *(short8*)&Btile[(nb << 4) + c][quad << 3];
                acc[ml][nb] = MFMA16(a, b, acc[ml][nb]);
            }
        }
        __syncthreads();
    }
    #pragma unroll
    for (int ml = 0; ml < 2; ++ml) {
        const int rl = (w << 5) + (ml << 4) + (quad << 2);
        #pragma unroll
        for (int nb = 0; nb < 4; ++nb) {
            const int col = n0 + (nb << 4) + c;
            const float bv = bias[col];
            #pragma unroll
            for (int r = 0; r < 4; ++r)
                Cf[(size_t)(rl + r) * 256 + col] = acc[ml][nb][r] + bv;
        }
    }
}

// ---------------------------------------------------------------------------
extern "C" void kernel_launch(void* const* d_in, const int* in_sizes, int n_in,
                              void* d_out, int out_size, void* d_ws, size_t ws_size,
                              hipStream_t stream)
{
    const float* x      = (const float*)d_in[0];
    const float* y      = (const float*)d_in[1];
    const float* Wq     = (const float*)d_in[2];
    const float* Wkv    = (const float*)d_in[3];
    const float* sr_w   = (const float*)d_in[4];
    const float* sr_b   = (const float*)d_in[5];
    const float* ln_g   = (const float*)d_in[6];
    const float* ln_b   = (const float*)d_in[7];
    const float* proj_w = (const float*)d_in[8];
    const float* proj_b = (const float*)d_in[9];

    unsigned short* p = (unsigned short*)d_ws;
    unsigned short* WqT   = p;  p += 65536;
    unsigned short* WkvT  = p;  p += 131072;
    unsigned short* projT = p;  p += 65536;
    unsigned short* BwT   = p;  p += 262144;
    unsigned short* redA  = p;  p += 671744;     // 2624x256 conv partial (K-half 0)
    unsigned short* redB  = p;  p += 671744;     // 2624x256 conv partial (K-half 1)
    unsigned short* qxb   = p;  p += 1638400;    // Q_x -> attn out (in place)
    unsigned short* qyb   = p;  p += 1048576;
    unsigned short* kswx  = p;  p += 409600;     // K_x swizzled [h][25 tiles][2048]
    unsigned short* vswx  = p;  p += 409600;     // V_x swizzled (sigma) [h][25][2048]
    unsigned short* kswy  = p;  p += 262144;     // [b][h][4][2048]
    unsigned short* vswy  = p;  p += 262144;
    unsigned short* kmsw  = p;  p += 65536;      // mean K_y swizzled [h][4][2048]
    unsigned short* vmsw  = p;  p += 65536;
    unsigned short* kpad  = p;  p += 2048;       // zero pad tile (K)
    unsigned short* vpad  = p;  p += 2048;       // zero pad tile (V), contiguous
    float* outx = (float*)d_out;
    float* outy = outx + 6400 * 256;

    prep_w<<<2064, 256, 0, stream>>>(Wq, Wkv, proj_w, sr_w, WqT, WkvT, projT, BwT, kpad);
    convq_kernel<<<656, 256, 0, stream>>>(x, y, BwT, WqT, redA, redB, qxb, qyb);
    kvln_kernel<<<328, 256, 0, stream>>>(redA, redB, WkvT, sr_b, ln_g, ln_b,
                                         kswx, vswx, kswy, vswy);
    kvmean_kernel<<<512, 256, 0, stream>>>(kswy, vswy, kmsw, vmsw);
    attn_mfma<<<1312, 256, 0, stream>>>(qxb, qyb, kswx, vswx, kmsw, vmsw,
                                        kswy, vswy, kpad, vpad);
    proj_mfma<<<328, 256, 0, stream>>>(qxb, qyb, projT, proj_b, outx, outy);
}